// Round 2
// baseline (670.073 us; speedup 1.0000x reference)
//
#include <hip/hip_runtime.h>

// Problem constants (b=2, c=64, h=w=96)
#define NPOS 9216      // h*w
#define NB 2
#define CCH 64
#define CQ 8

__device__ __forceinline__ float dot4(float4 a, float4 b) {
    return a.x*b.x + a.y*b.y + a.z*b.z + a.w*b.w;
}

// K1: 1x1 convs -> q [b][n][8], k [b][n][8], v [b][n][64]
__global__ __launch_bounds__(256) void qkv_kernel(
    const float* __restrict__ X, const float* __restrict__ Y,
    const float* __restrict__ Wq, const float* __restrict__ bq,
    const float* __restrict__ Wk, const float* __restrict__ bk,
    const float* __restrict__ Wv, const float* __restrict__ bv,
    float* __restrict__ q, float* __restrict__ k, float* __restrict__ v)
{
    __shared__ float wqkT[64 * 16];  // [c][o]: o<8 -> Wq[o][c], o>=8 -> Wk[o-8][c]
    __shared__ float wvT[64 * 64];   // [c][o] = Wv[o][c]
    int tid = threadIdx.x;
    for (int idx = tid; idx < 1024; idx += 256) {
        int c = idx >> 4, o = idx & 15;
        wqkT[idx] = (o < 8) ? Wq[o * 64 + c] : Wk[(o - 8) * 64 + c];
    }
    for (int idx = tid; idx < 4096; idx += 256) {
        int c = idx >> 6, o = idx & 63;
        wvT[idx] = Wv[o * 64 + c];
    }
    __syncthreads();

    int gid = blockIdx.x * 256 + tid;          // < 18432
    int b = gid / NPOS, n = gid % NPOS;

    float qa[8], ka[8], va[64];
    #pragma unroll
    for (int o = 0; o < 8; ++o) { qa[o] = bq[o]; ka[o] = bk[o]; }
    #pragma unroll
    for (int o = 0; o < 64; ++o) va[o] = bv[o];

    const float* Xb = X + (size_t)b * CCH * NPOS + n;
    const float* Yb = Y + (size_t)b * CCH * NPOS + n;
    for (int c = 0; c < 64; ++c) {
        float xv = Xb[(size_t)c * NPOS];
        float yv = Yb[(size_t)c * NPOS];
        const float4* wqk4 = (const float4*)(wqkT + c * 16);
        float4 w0 = wqk4[0], w1 = wqk4[1], w2 = wqk4[2], w3 = wqk4[3];
        qa[0] += w0.x * xv; qa[1] += w0.y * xv; qa[2] += w0.z * xv; qa[3] += w0.w * xv;
        qa[4] += w1.x * xv; qa[5] += w1.y * xv; qa[6] += w1.z * xv; qa[7] += w1.w * xv;
        ka[0] += w2.x * xv; ka[1] += w2.y * xv; ka[2] += w2.z * xv; ka[3] += w2.w * xv;
        ka[4] += w3.x * xv; ka[5] += w3.y * xv; ka[6] += w3.z * xv; ka[7] += w3.w * xv;
        const float4* wv4 = (const float4*)(wvT + c * 64);
        #pragma unroll
        for (int o4 = 0; o4 < 16; ++o4) {
            float4 w = wv4[o4];
            va[o4 * 4 + 0] += w.x * yv;
            va[o4 * 4 + 1] += w.y * yv;
            va[o4 * 4 + 2] += w.z * yv;
            va[o4 * 4 + 3] += w.w * yv;
        }
    }
    float4* qdst = (float4*)(q + (size_t)gid * 8);
    qdst[0] = make_float4(qa[0], qa[1], qa[2], qa[3]);
    qdst[1] = make_float4(qa[4], qa[5], qa[6], qa[7]);
    float4* kdst = (float4*)(k + (size_t)gid * 8);
    kdst[0] = make_float4(ka[0], ka[1], ka[2], ka[3]);
    kdst[1] = make_float4(ka[4], ka[5], ka[6], ka[7]);
    float4* vdst = (float4*)(v + (size_t)gid * 64);
    #pragma unroll
    for (int o4 = 0; o4 < 16; ++o4)
        vdst[o4] = make_float4(va[o4*4+0], va[o4*4+1], va[o4*4+2], va[o4*4+3]);
}

// K2: Z[b][j] = sum_i exp(q_i . k_j)   (softmax over i -> per-column denom)
// grid: (36 j-tiles, 8 i-chunks, 2 b); thread owns one j, loops 1152 i's.
__global__ __launch_bounds__(256) void zpass_kernel(
    const float* __restrict__ q, const float* __restrict__ k, float* __restrict__ Z)
{
    __shared__ float q_lds[1152 * 8];
    int b = blockIdx.z;
    int j = blockIdx.x * 256 + threadIdx.x;
    int i0 = blockIdx.y * 1152;

    const float4* krow = (const float4*)(k + ((size_t)b * NPOS + j) * 8);
    float4 ka = krow[0], kb = krow[1];

    const float4* qsrc = (const float4*)(q + ((size_t)b * NPOS + i0) * 8);
    float4* ql4 = (float4*)q_lds;
    for (int t = threadIdx.x; t < 2304; t += 256) ql4[t] = qsrc[t];
    __syncthreads();

    float z = 0.f;
    for (int i = 0; i < 1152; ++i) {
        float4 qa = ql4[i * 2], qb = ql4[i * 2 + 1];
        float s = dot4(qa, ka) + dot4(qb, kb);
        z += __expf(s);
    }
    atomicAdd(&Z[(size_t)b * NPOS + j], z);
}

// K2.5: v[j][:] *= 1/Z[j]
__global__ __launch_bounds__(256) void scalev_kernel(
    float* __restrict__ v, const float* __restrict__ Z)
{
    int gid = blockIdx.x * 256 + threadIdx.x;   // < 18432*16 float4s
    int row = gid >> 4;
    float rz = 1.0f / Z[row];
    float4* v4 = (float4*)v;
    float4 a = v4[gid];
    a.x *= rz; a.y *= rz; a.z *= rz; a.w *= rz;
    v4[gid] = a;
}

// K3: x[i][c] = sum_j exp(q_i.k_j) * vz[j][c]; atomicAdd into out (pre-init with Y,
// laid out [b][c][n] so the transpose+residual is folded in).
// grid: (18 i-tiles of 512, 16 j-splits of 576, 2 b); 2 rows per thread.
__global__ __launch_bounds__(256) void pass2_kernel(
    const float* __restrict__ q, const float* __restrict__ k,
    const float* __restrict__ vz, float* __restrict__ out)
{
    __shared__ float k_lds[64 * 8];
    __shared__ float vz_lds[64 * 64];
    int b = blockIdx.z;
    int tid = threadIdx.x;
    int i0 = blockIdx.x * 512 + tid;
    int i1 = i0 + 256;
    int j0 = blockIdx.y * 576;

    const float4* q0r = (const float4*)(q + ((size_t)b * NPOS + i0) * 8);
    float4 q0a = q0r[0], q0b = q0r[1];
    const float4* q1r = (const float4*)(q + ((size_t)b * NPOS + i1) * 8);
    float4 q1a = q1r[0], q1b = q1r[1];

    float4 acc0[16], acc1[16];
    #pragma unroll
    for (int t = 0; t < 16; ++t) {
        acc0[t] = make_float4(0.f, 0.f, 0.f, 0.f);
        acc1[t] = make_float4(0.f, 0.f, 0.f, 0.f);
    }

    float4* kl4 = (float4*)k_lds;
    float4* vl4 = (float4*)vz_lds;

    for (int ch = 0; ch < 9; ++ch) {
        int jb = j0 + ch * 64;
        __syncthreads();
        if (tid < 128)
            kl4[tid] = ((const float4*)(k + ((size_t)b * NPOS + jb) * 8))[tid];
        const float4* vsrc = (const float4*)(vz + ((size_t)b * NPOS + jb) * 64);
        #pragma unroll
        for (int t = 0; t < 4; ++t) vl4[tid + t * 256] = vsrc[tid + t * 256];
        __syncthreads();

        for (int jj = 0; jj < 64; ++jj) {
            float4 ka = kl4[jj * 2], kb = kl4[jj * 2 + 1];
            float s0 = dot4(q0a, ka) + dot4(q0b, kb);
            float s1 = dot4(q1a, ka) + dot4(q1b, kb);
            float p0 = __expf(s0);
            float p1 = __expf(s1);
            const float4* vr = vl4 + jj * 16;
            #pragma unroll
            for (int c4 = 0; c4 < 16; ++c4) {
                float4 vv = vr[c4];
                acc0[c4].x += p0 * vv.x; acc0[c4].y += p0 * vv.y;
                acc0[c4].z += p0 * vv.z; acc0[c4].w += p0 * vv.w;
                acc1[c4].x += p1 * vv.x; acc1[c4].y += p1 * vv.y;
                acc1[c4].z += p1 * vv.z; acc1[c4].w += p1 * vv.w;
            }
        }
    }

    float* x0 = out + (size_t)b * CCH * NPOS + i0;
    float* x1 = out + (size_t)b * CCH * NPOS + i1;
    #pragma unroll
    for (int c4 = 0; c4 < 16; ++c4) {
        atomicAdd(x0 + (size_t)(c4 * 4 + 0) * NPOS, acc0[c4].x);
        atomicAdd(x0 + (size_t)(c4 * 4 + 1) * NPOS, acc0[c4].y);
        atomicAdd(x0 + (size_t)(c4 * 4 + 2) * NPOS, acc0[c4].z);
        atomicAdd(x0 + (size_t)(c4 * 4 + 3) * NPOS, acc0[c4].w);
        atomicAdd(x1 + (size_t)(c4 * 4 + 0) * NPOS, acc1[c4].x);
        atomicAdd(x1 + (size_t)(c4 * 4 + 1) * NPOS, acc1[c4].y);
        atomicAdd(x1 + (size_t)(c4 * 4 + 2) * NPOS, acc1[c4].z);
        atomicAdd(x1 + (size_t)(c4 * 4 + 3) * NPOS, acc1[c4].w);
    }
}

extern "C" void kernel_launch(void* const* d_in, const int* in_sizes, int n_in,
                              void* d_out, int out_size, void* d_ws, size_t ws_size,
                              hipStream_t stream) {
    const float* X  = (const float*)d_in[0];
    const float* Y  = (const float*)d_in[1];
    const float* Wq = (const float*)d_in[2];
    const float* bq = (const float*)d_in[3];
    const float* Wk = (const float*)d_in[4];
    const float* bk = (const float*)d_in[5];
    const float* Wv = (const float*)d_in[6];
    const float* bv = (const float*)d_in[7];

    float* ws = (float*)d_ws;
    float* q = ws;                          // 2*9216*8  = 147456 floats
    float* k = q + (size_t)NB * NPOS * CQ;  // 147456
    float* v = k + (size_t)NB * NPOS * CQ;  // 2*9216*64 = 1179648
    float* Z = v + (size_t)NB * NPOS * CCH; // 18432
    // total ws use: ~6 MB

    hipMemsetAsync(Z, 0, (size_t)NB * NPOS * sizeof(float), stream);

    qkv_kernel<<<72, 256, 0, stream>>>(X, Y, Wq, bq, Wk, bk, Wv, bv, q, k, v);
    zpass_kernel<<<dim3(36, 8, NB), 256, 0, stream>>>(q, k, Z);
    scalev_kernel<<<1152, 256, 0, stream>>>(v, Z);

    // out = Y (residual, already [b][c][n]); pass2 atomically adds x^T into it.
    hipMemcpyAsync(d_out, Y, (size_t)NB * CCH * NPOS * sizeof(float),
                   hipMemcpyDeviceToDevice, stream);
    pass2_kernel<<<dim3(18, 16, NB), 256, 0, stream>>>(q, k, v, (float*)d_out);
}

// Round 3
// 205.230 us; speedup vs baseline: 3.2650x; 3.2650x over previous
//
#include <hip/hip_runtime.h>

// Problem constants (b=2, c=64, h=w=96)
#define NPOS 9216
#define NB 2
#define CCH 64

typedef __attribute__((ext_vector_type(8))) short short8;
typedef __attribute__((ext_vector_type(4))) float f32x4;

// f32 -> bf16 bits, round-to-nearest-even
__device__ __forceinline__ ushort f2bf(float x) {
    unsigned u = __builtin_bit_cast(unsigned, x);
    u += 0x7FFFu + ((u >> 16) & 1u);
    return (ushort)(u >> 16);
}

// ---------------------------------------------------------------------------
// K1: 1x1 convs. q,k -> bf16 [b][n][8] (MFMA-ready 16B rows); v -> f32 [b][n][64].
// Block = 256 thr = 64 positions x 4 slices. 288 blocks (>256 CUs).
// slice 0: q + v[0:16); slice 1: k + v[16:32); slices 2,3: v only.
// ---------------------------------------------------------------------------
__global__ __launch_bounds__(256) void qkv_kernel(
    const float* __restrict__ X, const float* __restrict__ Y,
    const float* __restrict__ Wq, const float* __restrict__ bq,
    const float* __restrict__ Wk, const float* __restrict__ bk,
    const float* __restrict__ Wv, const float* __restrict__ bv,
    ushort* __restrict__ qb, ushort* __restrict__ kb, float* __restrict__ v)
{
    __shared__ float wqkT[1024];   // [c][16]: o<8 Wq, o>=8 Wk
    __shared__ float wvT[4096];    // [c][64]
    int tid = threadIdx.x;
    for (int idx = tid; idx < 1024; idx += 256) {
        int c = idx >> 4, o = idx & 15;
        wqkT[idx] = (o < 8) ? Wq[o * 64 + c] : Wk[(o - 8) * 64 + c];
    }
    for (int idx = tid; idx < 4096; idx += 256) {
        int c = idx >> 6, o = idx & 63;
        wvT[idx] = Wv[o * 64 + c];
    }
    __syncthreads();

    int p = tid & 63, s = tid >> 6;          // s is wave-uniform
    int base = blockIdx.x * 64;
    int b = base / NPOS;
    int n = (base % NPOS) + p;

    float va[16], qk[8];
    #pragma unroll
    for (int o = 0; o < 16; ++o) va[o] = bv[s * 16 + o];
    #pragma unroll
    for (int o = 0; o < 8; ++o) qk[o] = 0.f;
    if (s == 0) {
        #pragma unroll
        for (int o = 0; o < 8; ++o) qk[o] = bq[o];
    } else if (s == 1) {
        #pragma unroll
        for (int o = 0; o < 8; ++o) qk[o] = bk[o];
    }

    const float* Xb = X + (size_t)b * CCH * NPOS + n;
    const float* Yb = Y + (size_t)b * CCH * NPOS + n;
    for (int c = 0; c < 64; ++c) {
        float yv = Yb[(size_t)c * NPOS];
        const float4* wv4 = (const float4*)(wvT + c * 64 + s * 16);
        #pragma unroll
        for (int o4 = 0; o4 < 4; ++o4) {
            float4 wv = wv4[o4];
            va[o4*4+0] += wv.x * yv; va[o4*4+1] += wv.y * yv;
            va[o4*4+2] += wv.z * yv; va[o4*4+3] += wv.w * yv;
        }
        if (s < 2) {
            float xv = Xb[(size_t)c * NPOS];
            const float4* wq4 = (const float4*)(wqkT + c * 16 + s * 8);
            float4 w0 = wq4[0], w1 = wq4[1];
            qk[0] += w0.x * xv; qk[1] += w0.y * xv;
            qk[2] += w0.z * xv; qk[3] += w0.w * xv;
            qk[4] += w1.x * xv; qk[5] += w1.y * xv;
            qk[6] += w1.z * xv; qk[7] += w1.w * xv;
        }
    }
    float4* vdst = (float4*)(v + ((size_t)b * NPOS + n) * 64 + s * 16);
    #pragma unroll
    for (int o4 = 0; o4 < 4; ++o4)
        vdst[o4] = make_float4(va[o4*4], va[o4*4+1], va[o4*4+2], va[o4*4+3]);
    if (s < 2) {
        short8 row;
        #pragma unroll
        for (int o = 0; o < 8; ++o) row[o] = (short)f2bf(qk[o]);
        ushort* dst = (s == 0 ? qb : kb) + ((size_t)b * NPOS + n) * 8;
        *(short8*)dst = row;
    }
}

// ---------------------------------------------------------------------------
// K2: Z[b][j] = sum_i exp(q_i . k_j) via MFMA.
// Wave owns 16 j (A-frag = k rows, g==0 lanes); streams q rows (B-frag).
// D layout: col=i=lane&15, row=j=4g+r. grid (144 j64-blocks, 4 i-quarters, b).
// ---------------------------------------------------------------------------
__global__ __launch_bounds__(256) void zpass_kernel(
    const ushort* __restrict__ qb, const ushort* __restrict__ kb,
    float* __restrict__ Z)
{
    int tid = threadIdx.x;
    int w = tid >> 6, l = tid & 63;
    int il = l & 15, g = l >> 4;
    int b = blockIdx.z;
    int jb = blockIdx.x * 64 + w * 16;
    const short8 zero8 = {0,0,0,0,0,0,0,0};
    const f32x4 cz = {0.f,0.f,0.f,0.f};

    short8 kf = zero8;
    if (g == 0) kf = *(const short8*)(kb + ((size_t)b * NPOS + jb + il) * 8);

    float za[4] = {0.f, 0.f, 0.f, 0.f};
    const ushort* qrow = qb + ((size_t)b * NPOS + blockIdx.y * 2304 + il) * 8;
    for (int is = 0; is < 144; ++is) {
        short8 qf = *(const short8*)(qrow + (size_t)is * 128);
        if (g != 0) qf = zero8;
        f32x4 sv = __builtin_amdgcn_mfma_f32_16x16x32_bf16(kf, qf, cz, 0, 0, 0);
        za[0] += __expf(sv[0]);
        za[1] += __expf(sv[1]);
        za[2] += __expf(sv[2]);
        za[3] += __expf(sv[3]);
    }
    #pragma unroll
    for (int r = 0; r < 4; ++r) {
        float x = za[r];
        x += __shfl_xor(x, 1, 16);
        x += __shfl_xor(x, 2, 16);
        x += __shfl_xor(x, 4, 16);
        x += __shfl_xor(x, 8, 16);
        za[r] = x;
    }
    if (il == 0) {
        #pragma unroll
        for (int r = 0; r < 4; ++r)
            atomicAdd(&Z[(size_t)b * NPOS + jb + g * 4 + r], za[r]);
    }
}

// ---------------------------------------------------------------------------
// K3: VzT[b][c][n] = bf16( v[b][n][c] / Z[b][n] )  (scale + transpose)
// ---------------------------------------------------------------------------
__global__ __launch_bounds__(256) void scalevT_kernel(
    const float* __restrict__ v, const float* __restrict__ Z,
    ushort* __restrict__ VzT)
{
    int tid = threadIdx.x;
    int p = tid & 63, s = tid >> 6;
    int base = blockIdx.x * 64;
    int b = base / NPOS;
    int n = (base % NPOS) + p;
    float rz = 1.0f / Z[(size_t)b * NPOS + n];
    const float4* vr = (const float4*)(v + ((size_t)b * NPOS + n) * 64 + s * 16);
    ushort* dst = VzT + (size_t)b * CCH * NPOS + n;
    #pragma unroll
    for (int q4 = 0; q4 < 4; ++q4) {
        float4 a = vr[q4];
        size_t c0 = s * 16 + q4 * 4;
        dst[(c0 + 0) * NPOS] = f2bf(a.x * rz);
        dst[(c0 + 1) * NPOS] = f2bf(a.y * rz);
        dst[(c0 + 2) * NPOS] = f2bf(a.z * rz);
        dst[(c0 + 3) * NPOS] = f2bf(a.w * rz);
    }
}

// ---------------------------------------------------------------------------
// K4: X^T[c][i] += sum_j exp(q_i.k_j) * VzT[c][j], MFMA both GEMMs.
// Block = 4 waves x 16 i; loops 36 j32-steps; VzT tile double-buffered in LDS;
// P goes through a swizzled per-wave LDS buffer (same-wave write->read).
// grid (144 i-blocks, 8 j-splits, b); atomicAdd into Y-preloaded out.
// ---------------------------------------------------------------------------
__global__ __launch_bounds__(256) void pass2_kernel(
    const ushort* __restrict__ qb, const ushort* __restrict__ kb,
    const ushort* __restrict__ VzT, float* __restrict__ out)
{
    __shared__ ushort vz_lds[2][2048];   // [64 c][32 j] bf16, linear
    __shared__ ushort p_lds[4][512];     // per-wave [16 i][32 j] bf16, slot-XOR swizzled
    int tid = threadIdx.x;
    int w = tid >> 6, l = tid & 63;
    int il = l & 15, g = l >> 4;
    int b = blockIdx.z;
    int ibase = blockIdx.x * 64 + w * 16;
    int j0 = blockIdx.y * 1152;

    const short8 zero8 = {0,0,0,0,0,0,0,0};
    const f32x4 cz = {0.f,0.f,0.f,0.f};

    short8 qf = zero8;
    if (g == 0) qf = *(const short8*)(qb + ((size_t)b * NPOS + ibase + il) * 8);

    f32x4 acc[4];
    #pragma unroll
    for (int cg = 0; cg < 4; ++cg) acc[cg] = cz;

    const ushort* kbb = kb + (size_t)b * NPOS * 8;
    // staging map: thread t -> (c = t>>2, jslot = t&3), 16B each
    int sc = tid >> 2, sslot = tid & 3;
    const ushort* vsrc = VzT + (size_t)b * CCH * NPOS + (size_t)sc * NPOS + j0 + sslot * 8;

    // prologue: stage tile 0
    *(float4*)&vz_lds[0][sc * 32 + sslot * 8] = *(const float4*)vsrc;
    __syncthreads();

    int swz = (il >> 1) & 3;
    ushort* pw = p_lds[w];

    for (int st = 0; st < 36; ++st) {
        int jb = j0 + st * 32;
        int cur = st & 1;
        bool more = (st + 1) < 36;
        float4 nv = {0.f,0.f,0.f,0.f};
        if (more) nv = *(const float4*)(vsrc + (size_t)(st + 1) * 32);   // prefetch next tile

        // S^T = K.Q^T (two 16-j MFMAs), K padded 8->32
        short8 kf0 = zero8, kf1 = zero8;
        if (g == 0) {
            kf0 = *(const short8*)(kbb + (size_t)(jb + il) * 8);
            kf1 = *(const short8*)(kbb + (size_t)(jb + 16 + il) * 8);
        }
        f32x4 s0 = __builtin_amdgcn_mfma_f32_16x16x32_bf16(kf0, qf, cz, 0, 0, 0);
        f32x4 s1 = __builtin_amdgcn_mfma_f32_16x16x32_bf16(kf1, qf, cz, 0, 0, 0);

        // exp -> bf16 pairs -> P_lds (row il; logical slot m*2+(g>>1), XOR swz)
        int rowoff = il * 32 + (g & 1) * 4;
        {
            int stored = ((g >> 1) ^ swz);
            unsigned u01 = (unsigned)f2bf(__expf(s0[0])) | ((unsigned)f2bf(__expf(s0[1])) << 16);
            unsigned u23 = (unsigned)f2bf(__expf(s0[2])) | ((unsigned)f2bf(__expf(s0[3])) << 16);
            *(unsigned*)&pw[rowoff + stored * 8 + 0] = u01;
            *(unsigned*)&pw[rowoff + stored * 8 + 2] = u23;
        }
        {
            int stored = ((2 | (g >> 1)) ^ swz);
            unsigned u01 = (unsigned)f2bf(__expf(s1[0])) | ((unsigned)f2bf(__expf(s1[1])) << 16);
            unsigned u23 = (unsigned)f2bf(__expf(s1[2])) | ((unsigned)f2bf(__expf(s1[3])) << 16);
            *(unsigned*)&pw[rowoff + stored * 8 + 0] = u01;
            *(unsigned*)&pw[rowoff + stored * 8 + 2] = u23;
        }

        // B-frag: P^T[j=8g+e][i=il]  (same-wave LDS read-back, swizzled slot)
        short8 pf = *(short8*)&pw[il * 32 + ((g ^ swz) * 8)];

        // PV: X^T[c][i] += VzT_tile . P^T   (4 c-groups)
        #pragma unroll
        for (int cg = 0; cg < 4; ++cg) {
            short8 af = *(short8*)&vz_lds[cur][(cg * 16 + il) * 32 + g * 8];
            acc[cg] = __builtin_amdgcn_mfma_f32_16x16x32_bf16(af, pf, acc[cg], 0, 0, 0);
        }

        // write prefetched tile to the other buffer; one barrier per step
        if (more) *(float4*)&vz_lds[cur ^ 1][sc * 32 + sslot * 8] = nv;
        __syncthreads();
    }

    // epilogue: D2 row = c-local = g*4+r, col = i = il
    float* ob = out + (size_t)b * CCH * NPOS + ibase + il;
    #pragma unroll
    for (int cg = 0; cg < 4; ++cg) {
        #pragma unroll
        for (int r = 0; r < 4; ++r) {
            int c = cg * 16 + g * 4 + r;
            atomicAdd(ob + (size_t)c * NPOS, acc[cg][r]);
        }
    }
}

extern "C" void kernel_launch(void* const* d_in, const int* in_sizes, int n_in,
                              void* d_out, int out_size, void* d_ws, size_t ws_size,
                              hipStream_t stream) {
    const float* X  = (const float*)d_in[0];
    const float* Y  = (const float*)d_in[1];
    const float* Wq = (const float*)d_in[2];
    const float* bq = (const float*)d_in[3];
    const float* Wk = (const float*)d_in[4];
    const float* bk = (const float*)d_in[5];
    const float* Wv = (const float*)d_in[6];
    const float* bv = (const float*)d_in[7];

    char* ws = (char*)d_ws;
    ushort* qb  = (ushort*)(ws);             // 2*9216*8 bf16   = 294912 B
    ushort* kbw = (ushort*)(ws + 294912);    // 294912 B
    ushort* VzT = (ushort*)(ws + 589824);    // 2*64*9216 bf16  = 2359296 B
    float*  v   = (float*) (ws + 2949120);   // 2*9216*64 f32   = 4718592 B
    float*  Z   = (float*) (ws + 7667712);   // 18432 f32       = 73728 B

    hipMemsetAsync(Z, 0, (size_t)NB * NPOS * sizeof(float), stream);

    qkv_kernel<<<288, 256, 0, stream>>>(X, Y, Wq, bq, Wk, bk, Wv, bv, qb, kbw, v);
    zpass_kernel<<<dim3(144, 4, NB), 256, 0, stream>>>(qb, kbw, Z);
    scalevT_kernel<<<288, 256, 0, stream>>>(v, Z, VzT);

    // out = Y (residual, [b][c][n]); pass2 atomically adds x^T into it.
    hipMemcpyAsync(d_out, Y, (size_t)NB * CCH * NPOS * sizeof(float),
                   hipMemcpyDeviceToDevice, stream);
    pass2_kernel<<<dim3(144, 8, NB), 256, 0, stream>>>(qb, kbw, VzT, (float*)d_out);
}